// Round 13
// baseline (51.532 us; speedup 1.0000x reference)
//
#include <hip/hip_runtime.h>
#include <hip/hip_bf16.h>
#include <hip/hip_fp16.h>

#define K_DIM 4096
#define N_DIM 14336
#define B_M   32
#define NSTEPS 128                    // K_DIM / 32 MFMA steps total
#define CHUNKS32 32                   // chunks of 128 ints per wave (full K)
#define NBLOCKS (N_DIM / 64)          // 224 blocks, 64 cols each

typedef __attribute__((ext_vector_type(8))) short short8;
typedef __attribute__((ext_vector_type(4))) float f32x4;
typedef __attribute__((ext_vector_type(2))) float f32x2;
typedef __attribute__((ext_vector_type(4))) int   i32x4;

static __device__ __forceinline__ short f2bf(float f) {
    union { float f; unsigned u; } v; v.f = f;
    unsigned r = v.u + 0x7FFFu + ((v.u >> 16) & 1u);   // RNE to bf16
    return (short)(r >> 16);
}

// Pre-swizzle x (32x4096 f32) into MFMA A-fragment order, bf16. Vectorized:
// one thread -> one short8. xa[((s*2+f)*64+l)*8+j] = bf16(x[16f+(l&15)][32s+8*(l>>4)+j])
__global__ __launch_bounds__(256) void prep_xa_kernel(const float* __restrict__ x,
                                                      short* __restrict__ xa) {
    int t2 = blockIdx.x * 256 + threadIdx.x;  // 0 .. 16383
    int l = t2 & 63;
    int f = (t2 >> 6) & 1;
    int s = t2 >> 7;                          // 0 .. 127
    int m = 16 * f + (l & 15);
    int k = 32 * s + 8 * (l >> 4);
    const float* src = x + (size_t)m * K_DIM + k;
    f32x4 v0 = *(const f32x4*)(src);
    f32x4 v1 = *(const f32x4*)(src + 4);
    short8 o;
    #pragma unroll
    for (int j = 0; j < 4; ++j) { o[j] = f2bf(v0[j]); o[j + 4] = f2bf(v1[j]); }
    *(short8*)(xa + (size_t)t2 * 8) = o;
}

// Burst-length experiment: block = 64 cols (4 n-tiles); wave w owns tile w with
// FULL K as 32 chunks of 128 ints. q staged 512 B/row contiguous (2x R12's
// 256 B) via 8 global_load_lds per chunk into per-wave double-buffered LDS
// (each wave consumes only rows it staged -> no barriers). Per chunk one
// uniform counted pair: {8 stage + 8 xa short8 + 1 scale f32x2} = 17 ops,
// issued for c+1 BEFORE the wait for c; steady wait vmcnt(17). Compute phase
// issues NO other vmem (R7 lesson). A/scale slots are parity-NAMED (R9/R11
// lesson: dynamic rings spill; launch_bounds(256,2) caps VGPR at 256).
// LDS chunk layout per wave: 16 rows x 32 units(16B), row stride 512 B; linear
// unit p at row r holds logical unit p ^ (r&7) (inverse swizzle on source).
// No split-K -> no epilogue reduce: each wave writes its tile directly.
__global__ __launch_bounds__(256, 2) void gemm_lds_kernel(
        const int* __restrict__ qw, const short* __restrict__ xa,
        const float* __restrict__ scales, const float* __restrict__ bias,
        float* __restrict__ out) {
    __shared__ int lds2[2][4][2048];  // [buf][wave][8 KB] = 64 KB

    const int tid  = threadIdx.x;
    const int w    = tid >> 6;
    const int lane = tid & 63;
    const int g    = lane >> 4;
    const int nl   = lane & 15;
    const int nw   = blockIdx.x * 64 + w * 16;   // this wave's tile base
    const int n    = nw + nl;

    const float* srow = scales + (size_t)n * (K_DIM / 64);  // f32 (harness upcasts fp16)

    // ---- q staging: 8 x global_load_lds(16B); instr i covers rows 2i,2i+1,
    //      512 B contiguous per row ----
    auto stage = [&](int* wbuf, int gc) {
        #pragma unroll
        for (int i = 0; i < 8; ++i) {
            int row = 2 * i + (lane >> 5);            // tile-local row 0..15
            int u   = (lane & 31) ^ (row & 7);        // inverse swizzle on source
            const int* src = qw + (size_t)(nw + row) * K_DIM + gc * 128 + u * 4;
            __builtin_amdgcn_global_load_lds(
                (const __attribute__((address_space(1))) void*)src,
                (__attribute__((address_space(3))) void*)(wbuf + i * 256),
                16, 0, 0);
        }
    };

    // ---- A prefetch: 8 x short8 per chunk (4 MFMA steps x 2 frags) ----
    auto loada = [&](short8 (&ar)[8], int gc) {
        const short* base = xa + (size_t)(gc * 4) * 1024 + lane * 8;
        #pragma unroll
        for (int s = 0; s < 4; ++s) {
            ar[2 * s]     = *(const short8*)(base + s * 1024);
            ar[2 * s + 1] = *(const short8*)(base + s * 1024 + 512);
        }
    };

    f32x4 acc0 = {0.f, 0.f, 0.f, 0.f};
    f32x4 acc1 = {0.f, 0.f, 0.f, 0.f};

    // ---- compute one 128-int chunk: 4 sub-steps, scale switches at k=64 ----
    auto compute = [&](const int* wbuf, const short8 (&ar)[8], f32x2 scp) {
        const int base = nl * 128;                    // row stride 512 B
        #pragma unroll
        for (int sp = 0; sp < 4; ++sp) {
            const float sc = (sp < 2) ? scp[0] : scp[1];
            int uA = 8 * sp + 2 * g;
            i32x4 qa = *(const i32x4*)(wbuf + base + ((uA    ) ^ (nl & 7)) * 4);
            i32x4 qb = *(const i32x4*)(wbuf + base + ((uA + 1) ^ (nl & 7)) * 4);

            short8 a0 = ar[2 * sp];
            short8 a1 = ar[2 * sp + 1];

            short8 bw;
            bw[0] = f2bf((float)qa[0] * sc);
            bw[1] = f2bf((float)qa[1] * sc);
            bw[2] = f2bf((float)qa[2] * sc);
            bw[3] = f2bf((float)qa[3] * sc);
            bw[4] = f2bf((float)qb[0] * sc);
            bw[5] = f2bf((float)qb[1] * sc);
            bw[6] = f2bf((float)qb[2] * sc);
            bw[7] = f2bf((float)qb[3] * sc);

            acc0 = __builtin_amdgcn_mfma_f32_16x16x32_bf16(a0, bw, acc0, 0, 0, 0);
            acc1 = __builtin_amdgcn_mfma_f32_16x16x32_bf16(a1, bw, acc1, 0, 0, 0);
        }
    };

    short8 aE[8], aO[8];              // named A slots: even / odd chunks
    f32x2  scE, scO;                  // named scale slots

    // prologue: pair 0 in flight
    stage(&lds2[0][w][0], 0);
    loada(aE, 0);
    scE = *(const f32x2*)(srow);

    #pragma unroll
    for (int c = 0; c < CHUNKS32; ++c) {
        // issue pair c+1 FIRST (buffer (c+1)&1 free: compute(c-1) done)
        if (c + 1 < CHUNKS32) {
            stage(&lds2[(c + 1) & 1][w][0], c + 1);
            if (c & 1) { loada(aE, c + 1); scE = *(const f32x2*)(srow + 2 * (c + 1)); }
            else       { loada(aO, c + 1); scO = *(const f32x2*)(srow + 2 * (c + 1)); }
        }
        // wait: pair c landed; pair c+1 (17 ops) may stay outstanding
        if (c < CHUNKS32 - 1) {
            asm volatile("s_waitcnt vmcnt(17)" ::: "memory");
        } else {
            asm volatile("s_waitcnt vmcnt(0)" ::: "memory");
        }

        const int* wbuf = &lds2[c & 1][w][0];
        if (c & 1) compute(wbuf, aO, scO); else compute(wbuf, aE, scE);
    }

    // ---- direct epilogue: no split-K, no barrier ----
    const float bv = bias[n];
    float* pp = out + n;
    #pragma unroll
    for (int r = 0; r < 4; ++r) {
        pp[(size_t)(4 * g + r) * N_DIM]      = acc0[r] + bv;   // C/D row = 4*(lane>>4)+r
        pp[(size_t)(16 + 4 * g + r) * N_DIM] = acc1[r] + bv;
    }
}

// Fallback (tiny ws): verified register-path kernel, full K per wave.
__global__ __launch_bounds__(64) void gemm_reg_kernel(
        const int* __restrict__ qw, const float* __restrict__ x,
        const float* __restrict__ scales, const float* __restrict__ bias,
        float* __restrict__ out) {
    const int lane = threadIdx.x;
    const int g = lane >> 4, nl = lane & 15;
    const int n = blockIdx.x * 16 + nl;
    const int* qrow = qw + (size_t)n * K_DIM + 8 * g;
    const float* srow = scales + (size_t)n * (K_DIM / 64);
    const float* xr0 = x + (size_t)nl * K_DIM + 8 * g;
    const float* xr1 = xr0 + (size_t)16 * K_DIM;
    f32x4 acc0 = {0.f,0.f,0.f,0.f}, acc1 = {0.f,0.f,0.f,0.f};
    for (int s = 0; s < NSTEPS; ++s) {
        i32x4 qa = *(const i32x4*)(qrow + 32 * s);
        i32x4 qb = *(const i32x4*)(qrow + 32 * s + 4);
        float sc = srow[s >> 1];
        f32x4 x00 = *(const f32x4*)(xr0 + 32 * s), x01 = *(const f32x4*)(xr0 + 32 * s + 4);
        f32x4 x10 = *(const f32x4*)(xr1 + 32 * s), x11 = *(const f32x4*)(xr1 + 32 * s + 4);
        short8 a0, a1, bw;
        #pragma unroll
        for (int j = 0; j < 4; ++j) { a0[j]=f2bf(x00[j]); a0[j+4]=f2bf(x01[j]);
                                      a1[j]=f2bf(x10[j]); a1[j+4]=f2bf(x11[j]);
                                      bw[j]=f2bf((float)qa[j]*sc); bw[j+4]=f2bf((float)qb[j]*sc); }
        acc0 = __builtin_amdgcn_mfma_f32_16x16x32_bf16(a0, bw, acc0, 0, 0, 0);
        acc1 = __builtin_amdgcn_mfma_f32_16x16x32_bf16(a1, bw, acc1, 0, 0, 0);
    }
    float bv = bias[n];
    float* pp = out + n;
    #pragma unroll
    for (int r = 0; r < 4; ++r) {
        pp[(size_t)(4 * g + r) * N_DIM]      = acc0[r] + bv;
        pp[(size_t)(16 + 4 * g + r) * N_DIM] = acc1[r] + bv;
    }
}

extern "C" void kernel_launch(void* const* d_in, const int* in_sizes, int n_in,
                              void* d_out, int out_size, void* d_ws, size_t ws_size,
                              hipStream_t stream) {
    const float* x    = (const float*)d_in[0];
    const int*   qw   = (const int*)d_in[1];
    const float* sc   = (const float*)d_in[2];   // fp16 in reference, delivered as f32
    const float* bias = (const float*)d_in[3];
    float* out = (float*)d_out;

    const size_t XA_BYTES = (size_t)B_M * K_DIM * 2;   // 256 KB

    if (ws_size >= XA_BYTES) {
        short* xa = (short*)d_ws;
        prep_xa_kernel<<<dim3(64), dim3(256), 0, stream>>>(x, xa);
        gemm_lds_kernel<<<dim3(NBLOCKS), dim3(256), 0, stream>>>(qw, xa, sc, bias, out);
    } else {
        gemm_reg_kernel<<<dim3(N_DIM / 16), dim3(64), 0, stream>>>(qw, x, sc, bias, out);
    }
}

// Round 14
// 45.562 us; speedup vs baseline: 1.1310x; 1.1310x over previous
//
#include <hip/hip_runtime.h>
#include <hip/hip_bf16.h>
#include <hip/hip_fp16.h>

#define K_DIM 4096
#define N_DIM 14336
#define B_M   32
#define NSTEPS 128                    // K_DIM / 32 MFMA steps total
#define NTILES (N_DIM / 16)           // 896 blocks, one n-tile each
#define WAVES 4                       // waves per block, one K-slice each
#define WCHUNKS 16                    // 64-int chunks per wave (K-slice = 1024 ints)

typedef __attribute__((ext_vector_type(8))) short short8;
typedef __attribute__((ext_vector_type(4))) float f32x4;
typedef __attribute__((ext_vector_type(4))) int   i32x4;

static __device__ __forceinline__ short f2bf(float f) {
    union { float f; unsigned u; } v; v.f = f;
    unsigned r = v.u + 0x7FFFu + ((v.u >> 16) & 1u);   // RNE to bf16
    return (short)(r >> 16);
}

// Pre-swizzle x (32x4096 f32) into MFMA A-fragment order, bf16. Vectorized:
// one thread -> one short8 (8 consecutive xa elements = fixed (s,f,l), j=0..7).
// xa[((s*2+f)*64 + l)*8 + j] = bf16(x[16*f + (l&15)][32*s + 8*(l>>4) + j])
__global__ __launch_bounds__(256) void prep_xa_kernel(const float* __restrict__ x,
                                                      short* __restrict__ xa) {
    int t2 = blockIdx.x * 256 + threadIdx.x;  // 0 .. 16383
    int l = t2 & 63;
    int f = (t2 >> 6) & 1;
    int s = t2 >> 7;                          // 0 .. 127
    int m = 16 * f + (l & 15);
    int k = 32 * s + 8 * (l >> 4);
    const float* src = x + (size_t)m * K_DIM + k;
    f32x4 v0 = *(const f32x4*)(src);
    f32x4 v1 = *(const f32x4*)(src + 4);
    short8 o;
    #pragma unroll
    for (int j = 0; j < 4; ++j) { o[j] = f2bf(v0[j]); o[j + 4] = f2bf(v1[j]); }
    *(short8*)(xa + (size_t)t2 * 8) = o;
}

// One block = one 16-col n-tile; wave w owns K-slice [w*1024,(w+1)*1024) as 16
// chunks of 64 ints. DOUBLE-buffered LDS (32 KB/block), 4 blocks/CU. Per chunk
// one uniform prefetch PAIR: 4 global_load_lds (q) + 4 short8 register loads
// (xa A-frags, 2 named slots by parity — R9/R11 lesson: bigger rings spill and
// scratch traffic drains the counted pipeline). Pair c+1 issued BEFORE the
// wait for pair c; steady-state wait vmcnt(8) = pair c landed, pair c+1 in
// flight. Compute issues NO other vmem (R7 lesson: consume-now global loads
// force a full drain — vmcnt counts in issue order).
// LDS q-chunk layout per wave: 16 rows x 16 units(16B); linear unit p at row r
// holds logical unit p ^ (r&7) (inverse swizzle applied on global source).
__global__ __launch_bounds__(256, 4) void gemm_lds_kernel(
        const int* __restrict__ qw, const short* __restrict__ xa,
        const float* __restrict__ scales, const float* __restrict__ bias,
        float* __restrict__ out) {
    __shared__ int lds2[2][4096];     // 2 bufs x (4 waves x 1024 ints) = 32 KB

    const int tid  = threadIdx.x;
    const int w    = tid >> 6;
    const int lane = tid & 63;
    const int g    = lane >> 4;
    const int nl   = lane & 15;
    const int n0   = blockIdx.x * 16;
    const int n    = n0 + nl;
    const int gc0  = w * WCHUNKS;     // this wave's first chunk index

    const float* srow = scales + (size_t)n * (K_DIM / 64);  // f32 (harness upcasts fp16)

    // ---- q staging: 4 x global_load_lds(16B) per chunk (instr i -> rows 4i..4i+3) ----
    auto stage = [&](int* wbuf, int gc) {
        #pragma unroll
        for (int i = 0; i < 4; ++i) {
            int row = i * 4 + (lane >> 4);            // tile-local row 0..15
            int l   = (lane & 15) ^ (row & 7);        // inverse swizzle on source
            const int* src = qw + (size_t)(n0 + row) * K_DIM + gc * 64 + l * 4;
            __builtin_amdgcn_global_load_lds(
                (const __attribute__((address_space(1))) void*)src,
                (__attribute__((address_space(3))) void*)(wbuf + i * 256),
                16, 0, 0);
        }
    };

    // ---- A prefetch: 4 x short8 register loads per chunk (2 steps x 2 frags) ----
    auto loada = [&](short8 (&ar)[4], int gc) {
        const short* base = xa + (size_t)(gc * 2) * 1024 + lane * 8;
        ar[0] = *(const short8*)(base);
        ar[1] = *(const short8*)(base + 512);
        ar[2] = *(const short8*)(base + 1024);
        ar[3] = *(const short8*)(base + 1536);
    };

    f32x4 acc0 = {0.f, 0.f, 0.f, 0.f};
    f32x4 acc1 = {0.f, 0.f, 0.f, 0.f};

    // ---- compute one chunk from staged LDS q + a named A slot ----
    auto compute = [&](const int* wbuf, const short8 (&ar)[4], float sc) {
        const int base = nl * 64;                     // this lane's LDS row
        #pragma unroll
        for (int sp = 0; sp < 2; ++sp) {
            int uA = 8 * sp + 2 * g;
            i32x4 qa = *(const i32x4*)(wbuf + base + ((uA    ) ^ (nl & 7)) * 4);
            i32x4 qb = *(const i32x4*)(wbuf + base + ((uA + 1) ^ (nl & 7)) * 4);

            short8 a0 = ar[2 * sp];
            short8 a1 = ar[2 * sp + 1];

            short8 bw;
            bw[0] = f2bf((float)qa[0] * sc);
            bw[1] = f2bf((float)qa[1] * sc);
            bw[2] = f2bf((float)qa[2] * sc);
            bw[3] = f2bf((float)qa[3] * sc);
            bw[4] = f2bf((float)qb[0] * sc);
            bw[5] = f2bf((float)qb[1] * sc);
            bw[6] = f2bf((float)qb[2] * sc);
            bw[7] = f2bf((float)qb[3] * sc);

            acc0 = __builtin_amdgcn_mfma_f32_16x16x32_bf16(a0, bw, acc0, 0, 0, 0);
            acc1 = __builtin_amdgcn_mfma_f32_16x16x32_bf16(a1, bw, acc1, 0, 0, 0);
        }
    };

    // hoist scales, then drain so they never pollute the counted pipeline
    f32x4 s4[4];
    #pragma unroll
    for (int i = 0; i < 4; ++i) s4[i] = *(const f32x4*)(srow + gc0 + i * 4);
    asm volatile("s_waitcnt vmcnt(0)" ::: "memory");

    short8 aE[4], aO[4];              // named A slots: even / odd chunks

    // prologue: pair 0 in flight
    stage(lds2[0] + w * 1024, gc0 + 0);
    loada(aE, gc0 + 0);

    #pragma unroll
    for (int c = 0; c < WCHUNKS; ++c) {
        // issue pair c+1 FIRST (buffer (c+1)&1 free: compute(c-1) done)
        if (c + 1 < WCHUNKS) {
            stage(lds2[(c + 1) & 1] + w * 1024, gc0 + c + 1);
            if (c & 1) loada(aE, gc0 + c + 1); else loada(aO, gc0 + c + 1);
        }
        // wait: pair c landed; pair c+1 (8 ops) may stay outstanding
        if (c < WCHUNKS - 1) {
            asm volatile("s_waitcnt vmcnt(8)" ::: "memory");
        } else {
            asm volatile("s_waitcnt vmcnt(0)" ::: "memory");
        }

        const int*  wbuf = lds2[c & 1] + w * 1024;
        const float sc   = s4[c >> 2][c & 3];         // c is unroll-constant
        if (c & 1) compute(wbuf, aO, sc); else compute(wbuf, aE, sc);
    }

    // ---- cross-wave reduce: acc -> own LDS region (stride-9 pad: conflict-free),
    //      barrier, tree-sum ----
    float* fb = (float*)(lds2[0] + w * 1024);
    #pragma unroll
    for (int r = 0; r < 4; ++r) { fb[lane * 9 + r] = acc0[r]; fb[lane * 9 + 4 + r] = acc1[r]; }
    __syncthreads();

    // 256 threads x 2 components: thread handles (lane2, rr) and (lane2, rr+4)
    const int lane2 = tid & 63;
    const int rr    = tid >> 6;           // 0..3
    const int g2    = lane2 >> 4;
    const int n2    = n0 + (lane2 & 15);
    float s1 = 0.f, s2 = 0.f;
    #pragma unroll
    for (int ww = 0; ww < WAVES; ++ww) {
        const float* fw = (const float*)(lds2[0] + ww * 1024);
        s1 += fw[lane2 * 9 + rr];
        s2 += fw[lane2 * 9 + 4 + rr];
    }
    const float bv = bias[n2];
    out[(size_t)(4 * g2 + rr) * N_DIM + n2]      = s1 + bv;   // C/D row = 4*(lane>>4)+r
    out[(size_t)(16 + 4 * g2 + rr) * N_DIM + n2] = s2 + bv;
}

// Fallback (tiny ws): verified register-path kernel, full K per wave.
__global__ __launch_bounds__(64) void gemm_reg_kernel(
        const int* __restrict__ qw, const float* __restrict__ x,
        const float* __restrict__ scales, const float* __restrict__ bias,
        float* __restrict__ out) {
    const int lane = threadIdx.x;
    const int g = lane >> 4, nl = lane & 15;
    const int n = blockIdx.x * 16 + nl;
    const int* qrow = qw + (size_t)n * K_DIM + 8 * g;
    const float* srow = scales + (size_t)n * (K_DIM / 64);
    const float* xr0 = x + (size_t)nl * K_DIM + 8 * g;
    const float* xr1 = xr0 + (size_t)16 * K_DIM;
    f32x4 acc0 = {0.f,0.f,0.f,0.f}, acc1 = {0.f,0.f,0.f,0.f};
    for (int s = 0; s < NSTEPS; ++s) {
        i32x4 qa = *(const i32x4*)(qrow + 32 * s);
        i32x4 qb = *(const i32x4*)(qrow + 32 * s + 4);
        float sc = srow[s >> 1];
        f32x4 x00 = *(const f32x4*)(xr0 + 32 * s), x01 = *(const f32x4*)(xr0 + 32 * s + 4);
        f32x4 x10 = *(const f32x4*)(xr1 + 32 * s), x11 = *(const f32x4*)(xr1 + 32 * s + 4);
        short8 a0, a1, bw;
        #pragma unroll
        for (int j = 0; j < 4; ++j) { a0[j]=f2bf(x00[j]); a0[j+4]=f2bf(x01[j]);
                                      a1[j]=f2bf(x10[j]); a1[j+4]=f2bf(x11[j]);
                                      bw[j]=f2bf((float)qa[j]*sc); bw[j+4]=f2bf((float)qb[j]*sc); }
        acc0 = __builtin_amdgcn_mfma_f32_16x16x32_bf16(a0, bw, acc0, 0, 0, 0);
        acc1 = __builtin_amdgcn_mfma_f32_16x16x32_bf16(a1, bw, acc1, 0, 0, 0);
    }
    float bv = bias[n];
    float* pp = out + n;
    #pragma unroll
    for (int r = 0; r < 4; ++r) {
        pp[(size_t)(4 * g + r) * N_DIM]      = acc0[r] + bv;
        pp[(size_t)(16 + 4 * g + r) * N_DIM] = acc1[r] + bv;
    }
}

extern "C" void kernel_launch(void* const* d_in, const int* in_sizes, int n_in,
                              void* d_out, int out_size, void* d_ws, size_t ws_size,
                              hipStream_t stream) {
    const float* x    = (const float*)d_in[0];
    const int*   qw   = (const int*)d_in[1];
    const float* sc   = (const float*)d_in[2];   // fp16 in reference, delivered as f32
    const float* bias = (const float*)d_in[3];
    float* out = (float*)d_out;

    const size_t XA_BYTES = (size_t)B_M * K_DIM * 2;   // 256 KB

    if (ws_size >= XA_BYTES) {
        short* xa = (short*)d_ws;
        prep_xa_kernel<<<dim3(64), dim3(256), 0, stream>>>(x, xa);
        gemm_lds_kernel<<<dim3(NTILES), dim3(256), 0, stream>>>(qw, xa, sc, bias, out);
    } else {
        gemm_reg_kernel<<<dim3(NTILES), dim3(64), 0, stream>>>(qw, x, sc, bias, out);
    }
}